// Round 4
// baseline (17308.992 us; speedup 1.0000x reference)
//
#include <hip/hip_runtime.h>
#include <hip/hip_bf16.h>
#include <hip/hip_cooperative_groups.h>

namespace cg = cooperative_groups;

typedef __attribute__((ext_vector_type(8))) short short8;
typedef __attribute__((ext_vector_type(4))) float f32x4;
typedef unsigned long long ull;

static constexpr int E_ = 512, H_ = 1024, S_ = 512, B_ = 64, NT_ = 13;
static constexpr int G4H = 4 * H_;  // 4096
static constexpr int NWG = 64;      // active recurrence workgroups
static constexpr int RPW = 64;      // packed gate rows per WG

// ---- workspace layout ----
static constexpr size_t WIH_ELEMS = (size_t)NT_ * G4H * E_;
static constexpr size_t WHH_ELEMS = (size_t)NT_ * G4H * H_;
static constexpr size_t X_ELEMS   = (size_t)S_ * B_ * E_;
static constexpr size_t BIAS_ELEMS = (size_t)NT_ * G4H;
static constexpr size_t HBUF_ELEMS = (size_t)B_ * H_;

static constexpr size_t OFF_WIH  = 0;
static constexpr size_t OFF_WHH  = OFF_WIH + WIH_ELEMS * 2;
static constexpr size_t OFF_X    = OFF_WHH + WHH_ELEMS * 2;
static constexpr size_t OFF_BIAS = OFF_X + X_ELEMS * 2;
static constexpr size_t OFF_H    = OFF_BIAS + BIAS_ELEMS * 4;
static constexpr size_t OFF_FLAGS = OFF_H + 2 * HBUF_ELEMS * 2;  // uint[256]

static constexpr int TL_STRIDE = 68;  // floats; bank-spread pad

__device__ inline short f2bf(float x) {
  __hip_bfloat16 h = __float2bfloat16(x);
  return __builtin_bit_cast(short, h);
}
__device__ inline float b2f(short s) {
  unsigned u = ((unsigned)(unsigned short)s) << 16;
  return __builtin_bit_cast(float, u);
}
__device__ inline short8 cvt8(const float* src) {
  f32x4 a = *(const f32x4*)src;
  f32x4 b = *(const f32x4*)(src + 4);
  short8 o;
  o[0] = f2bf(a[0]); o[1] = f2bf(a[1]); o[2] = f2bf(a[2]); o[3] = f2bf(a[3]);
  o[4] = f2bf(b[0]); o[5] = f2bf(b[1]); o[6] = f2bf(b[2]); o[7] = f2bf(b[3]);
  return o;
}
__device__ inline float sigm(float x) { return 1.f / (1.f + __expf(-x)); }

__device__ inline int unpack_row(int p) {
  return ((p >> 2) & 3) * H_ + (p >> 4) * 4 + (p & 3);
}

// x-contribution for the WG's 4 gate tiles (gt = 0..3). A = x rows (this
// wave's 16 batch rows), B = W_ih packed rows wg*64 + gt*16 + arow.
__device__ inline void xgemm4(const short* __restrict__ x_bf,
                              const short* __restrict__ wih_pk,
                              int t, int tag, int wg, int m0, int arow, int kq,
                              f32x4& o0, f32x4& o1, f32x4& o2, f32x4& o3) {
  const short* ap = x_bf + ((size_t)t * B_ + m0 + arow) * E_ + kq;
  short8 av[16];
#pragma unroll
  for (int i = 0; i < 16; ++i) av[i] = *(const short8*)(ap + i * 32);
  const short* b0p = wih_pk + ((size_t)tag * G4H + wg * RPW + arow) * E_ + kq;
  const short* b1p = b0p + (size_t)16 * E_;
  const short* b2p = b0p + (size_t)32 * E_;
  const short* b3p = b0p + (size_t)48 * E_;
  f32x4 a0 = {0.f, 0.f, 0.f, 0.f}, a1 = {0.f, 0.f, 0.f, 0.f};
  f32x4 a2 = {0.f, 0.f, 0.f, 0.f}, a3 = {0.f, 0.f, 0.f, 0.f};
#pragma unroll
  for (int i = 0; i < 16; ++i) {
    a0 = __builtin_amdgcn_mfma_f32_16x16x32_bf16(av[i], *(const short8*)(b0p + i * 32), a0, 0, 0, 0);
    a1 = __builtin_amdgcn_mfma_f32_16x16x32_bf16(av[i], *(const short8*)(b1p + i * 32), a1, 0, 0, 0);
    a2 = __builtin_amdgcn_mfma_f32_16x16x32_bf16(av[i], *(const short8*)(b2p + i * 32), a2, 0, 0, 0);
    a3 = __builtin_amdgcn_mfma_f32_16x16x32_bf16(av[i], *(const short8*)(b3p + i * 32), a3, 0, 0, 0);
  }
  o0 = a0; o1 = a1; o2 = a2; o3 = a3;
}

__global__ __launch_bounds__(256, 1) void lstm_tag_kernel(
    const int* __restrict__ tokens, const int* __restrict__ tags,
    const float* __restrict__ emb_w,
    const float* __restrict__ W_ih, const float* __restrict__ W_hh,
    const float* __restrict__ b_ih, const float* __restrict__ b_hh,
    const float* __restrict__ W1, const float* __restrict__ b1,
    const float* __restrict__ W2, const float* __restrict__ b2,
    float* __restrict__ out,
    short* __restrict__ wih_pk, short* __restrict__ whh_pk,
    short* __restrict__ x_bf, float* __restrict__ bias_pk,
    short* __restrict__ h_bf, unsigned* __restrict__ flags) {
  cg::grid_group grid = cg::this_grid();
  const int tid = threadIdx.x;
  const int wg = blockIdx.x;
  const int lane = tid & 63;
  const int ll = tid >> 6;
  const int gw = wg * 4 + ll;
  const int gtid = wg * 256 + tid;

  __shared__ float lds_tile[4 * 16 * TL_STRIDE];  // 17.4 KB: gate exchange
  __shared__ ull lds_hst_q[256];                  // 2 KB: packed h staging
  short* lds_hst = (short*)lds_hst_q;

  // ================= Phase 0: pre-pass (all 256 WGs) =================
  for (int row = gw; row < NT_ * G4H; row += 1024) {
    int tag = row >> 12, p = row & 4095, r = unpack_row(p);
    const float* src = W_ih + ((size_t)tag * G4H + r) * E_ + lane * 8;
    short* dst = wih_pk + ((size_t)tag * G4H + p) * E_ + lane * 8;
    *(short8*)dst = cvt8(src);
  }
  for (int row = gw; row < NT_ * G4H; row += 1024) {
    int tag = row >> 12, p = row & 4095, r = unpack_row(p);
    const float* src = W_hh + ((size_t)tag * G4H + r) * H_;
    short* dst = whh_pk + ((size_t)tag * G4H + p) * H_;
    *(short8*)(dst + lane * 8) = cvt8(src + lane * 8);
    *(short8*)(dst + 512 + lane * 8) = cvt8(src + 512 + lane * 8);
  }
  for (int idx = gtid; idx < NT_ * G4H; idx += 65536) {
    int tag = idx >> 12;
    int r = unpack_row(idx & 4095);
    bias_pk[idx] = b_ih[tag * G4H + r] + b_hh[tag * G4H + r];
  }
  for (int row = gw; row < S_ * B_; row += 1024) {
    int t = row >> 6, b = row & 63;
    int tok = tokens[b * S_ + t];
    const float* src = emb_w + (size_t)tok * E_ + lane * 8;
    short* dst = x_bf + (size_t)row * E_ + lane * 8;
    *(short8*)dst = cvt8(src);
  }
  ((int*)h_bf)[gtid] = 0;  // zero both h buffers
  if (gtid < 256) flags[gtid] = 0u;

  grid.sync();  // packed data + zeroed h/flags visible everywhere

  if (wg < NWG) {
    // ========== Phase 1: recurrence (64 WGs, waves independent) ==========
    const int arow = lane & 15;
    const int kq = (lane >> 4) * 8;
    const int m0 = ll * 16;  // wave's 16 batch rows

    int tag = tags[0];
    f32x4 ax0, ax1, ax2, ax3;
    xgemm4(x_bf, wih_pk, 0, tag, wg, m0, arow, kq, ax0, ax1, ax2, ax3);
    float bs0, bs1, bs2, bs3;
    {
      const float* bp_ = bias_pk + tag * G4H + wg * RPW + arow;
      bs0 = bp_[0]; bs1 = bp_[16]; bs2 = bp_[32]; bs3 = bp_[48];
    }

    float c0 = 0.f, c1 = 0.f, c2 = 0.f, c3 = 0.f;

    for (int t = 0; t < S_; ++t) {
      const short* Acur = h_bf + (size_t)(t & 1) * HBUF_ELEMS;
      short* Anext = h_bf + (size_t)((t + 1) & 1) * HBUF_ELEMS;

      // ---- h A-tile: coherent loads (this wave's 16 batch rows) ----
      ull* ab = (ull*)(Acur + (size_t)(m0 + arow) * H_);
      const int ib = kq >> 2;
      short8 ah[32];
#pragma unroll
      for (int i = 0; i < 32; ++i) {
        ull lo = __hip_atomic_load(ab + ib + i * 8, __ATOMIC_RELAXED,
                                   __HIP_MEMORY_SCOPE_AGENT);
        ull hi = __hip_atomic_load(ab + ib + i * 8 + 1, __ATOMIC_RELAXED,
                                   __HIP_MEMORY_SCOPE_AGENT);
        union { ull q[2]; short8 s; } u;
        u.q[0] = lo; u.q[1] = hi;
        ah[i] = u.s;
      }

      // ---- h-GEMM: 4 gate tiles, B-frags direct from global (L2-hot) ----
      f32x4 a0 = ax0, a1 = ax1, a2 = ax2, a3 = ax3;
      const short* b0p = whh_pk + ((size_t)tag * G4H + wg * RPW + arow) * H_ + kq;
      const short* b1p = b0p + (size_t)16 * H_;
      const short* b2p = b0p + (size_t)32 * H_;
      const short* b3p = b0p + (size_t)48 * H_;
#pragma unroll
      for (int i = 0; i < 32; ++i) {
        a0 = __builtin_amdgcn_mfma_f32_16x16x32_bf16(ah[i], *(const short8*)(b0p + i * 32), a0, 0, 0, 0);
        a1 = __builtin_amdgcn_mfma_f32_16x16x32_bf16(ah[i], *(const short8*)(b1p + i * 32), a1, 0, 0, 0);
        a2 = __builtin_amdgcn_mfma_f32_16x16x32_bf16(ah[i], *(const short8*)(b2p + i * 32), a2, 0, 0, 0);
        a3 = __builtin_amdgcn_mfma_f32_16x16x32_bf16(ah[i], *(const short8*)(b3p + i * 32), a3, 0, 0, 0);
      }

      // ---- gate exchange (wave-local): tl[batch 16][gate 64] ----
      float* tlw = lds_tile + ll * (16 * TL_STRIDE);
#pragma unroll
      for (int r = 0; r < 4; ++r) {
        int br = ((lane >> 4) * 4 + r) * TL_STRIDE;
        tlw[br + 0 * 16 + arow] = a0[r] + bs0;
        tlw[br + 1 * 16 + arow] = a1[r] + bs1;
        tlw[br + 2 * 16 + arow] = a2[r] + bs2;
        tlw[br + 3 * 16 + arow] = a3[r] + bs3;
      }
      __builtin_amdgcn_wave_barrier();
      {
        const int uu = lane & 3, b = lane >> 2;
        const float* rp = tlw + b * TL_STRIDE;
        float iv, fv, gv, ov, cn;
        iv = rp[0 + uu]; fv = rp[4 + uu]; gv = rp[8 + uu]; ov = rp[12 + uu];
        cn = sigm(fv) * c0 + sigm(iv) * tanhf(gv); c0 = cn;
        lds_hst[(m0 + b) * 16 + 0 + uu] = f2bf(sigm(ov) * tanhf(cn));
        iv = rp[16 + uu]; fv = rp[20 + uu]; gv = rp[24 + uu]; ov = rp[28 + uu];
        cn = sigm(fv) * c1 + sigm(iv) * tanhf(gv); c1 = cn;
        lds_hst[(m0 + b) * 16 + 4 + uu] = f2bf(sigm(ov) * tanhf(cn));
        iv = rp[32 + uu]; fv = rp[36 + uu]; gv = rp[40 + uu]; ov = rp[44 + uu];
        cn = sigm(fv) * c2 + sigm(iv) * tanhf(gv); c2 = cn;
        lds_hst[(m0 + b) * 16 + 8 + uu] = f2bf(sigm(ov) * tanhf(cn));
        iv = rp[48 + uu]; fv = rp[52 + uu]; gv = rp[56 + uu]; ov = rp[60 + uu];
        cn = sigm(fv) * c3 + sigm(iv) * tanhf(gv); c3 = cn;
        lds_hst[(m0 + b) * 16 + 12 + uu] = f2bf(sigm(ov) * tanhf(cn));
      }
      __builtin_amdgcn_wave_barrier();

      // ---- publish own 16 batch rows × WG's 16 units, then version flag ----
      {
        const int row = m0 + (lane >> 2);
        ull v = lds_hst_q[row * 4 + (lane & 3)];
        __hip_atomic_store((ull*)(Anext + (size_t)row * H_ + wg * 16 + (lane & 3) * 4),
                           v, __ATOMIC_RELAXED, __HIP_MEMORY_SCOPE_AGENT);
        asm volatile("s_waitcnt vmcnt(0)" ::: "memory");  // stores at coherence pt
        if (lane == 0)
          __hip_atomic_store(flags + gw, (unsigned)(t + 1), __ATOMIC_RELAXED,
                             __HIP_MEMORY_SCOPE_AGENT);
      }

      // ---- shadow work for t+1 (overlaps others' compute + our spin) ----
      if (t < S_ - 1) {
        const int tagn = tags[t + 1];
        xgemm4(x_bf, wih_pk, t + 1, tagn, wg, m0, arow, kq, ax0, ax1, ax2, ax3);
        const float* bp_ = bias_pk + tagn * G4H + wg * RPW + arow;
        bs0 = bp_[0]; bs1 = bp_[16]; bs2 = bp_[32]; bs3 = bp_[48];
        tag = tagn;
      }

      // ---- per-wave flag barrier: all 256 wave-flags >= t+1 ----
      {
        const unsigned target = (unsigned)(t + 1);
        for (;;) {
          unsigned v0 = __hip_atomic_load(flags + lane, __ATOMIC_RELAXED,
                                          __HIP_MEMORY_SCOPE_AGENT);
          unsigned v1 = __hip_atomic_load(flags + lane + 64, __ATOMIC_RELAXED,
                                          __HIP_MEMORY_SCOPE_AGENT);
          unsigned v2 = __hip_atomic_load(flags + lane + 128, __ATOMIC_RELAXED,
                                          __HIP_MEMORY_SCOPE_AGENT);
          unsigned v3 = __hip_atomic_load(flags + lane + 192, __ATOMIC_RELAXED,
                                          __HIP_MEMORY_SCOPE_AGENT);
          unsigned m01 = v0 < v1 ? v0 : v1;
          unsigned m23 = v2 < v3 ? v2 : v3;
          unsigned mn = m01 < m23 ? m01 : m23;
          if (__all((int)(mn >= target))) break;
          __builtin_amdgcn_s_sleep(1);
        }
      }
    }
  } else {
    // Idle WGs (64..255): low-rate wait so the flag lines stay cool.
    if (tid == 0) {
      while (__hip_atomic_load(flags, __ATOMIC_RELAXED,
                               __HIP_MEMORY_SCOPE_AGENT) < (unsigned)S_)
        __builtin_amdgcn_s_sleep(127);
    }
    __syncthreads();
  }

  grid.sync();  // full fence: final h coherent for plain loads below

  // ================= Phase 2: FFN head =================
  if (wg < B_) {
    const int b = wg, d = tid;
    const short* hrow = h_bf + (size_t)(S_ & 1) * HBUF_ELEMS + (size_t)b * H_;
    const float* w1r = W1 + (size_t)d * H_;
    float s = b1[d];
#pragma unroll 4
    for (int k = 0; k < H_; k += 8) {
      short8 hv = *(const short8*)(hrow + k);
      f32x4 w0 = *(const f32x4*)(w1r + k);
      f32x4 w1v = *(const f32x4*)(w1r + k + 4);
      s += w0[0] * b2f(hv[0]) + w0[1] * b2f(hv[1]) + w0[2] * b2f(hv[2]) +
           w0[3] * b2f(hv[3]) + w1v[0] * b2f(hv[4]) + w1v[1] * b2f(hv[5]) +
           w1v[2] * b2f(hv[6]) + w1v[3] * b2f(hv[7]);
    }
    s = fmaxf(s, 0.f);
    __shared__ float red[256];
    red[tid] = s * W2[d];
    __syncthreads();
    for (int off = 128; off > 0; off >>= 1) {
      if (tid < off) red[tid] += red[tid + off];
      __syncthreads();
    }
    if (tid == 0) out[b] = 1.f / (1.f + __expf(-(red[0] + b2[0])));
  }
}

extern "C" void kernel_launch(void* const* d_in, const int* in_sizes, int n_in,
                              void* d_out, int out_size, void* d_ws, size_t ws_size,
                              hipStream_t stream) {
  const int* tokens = (const int*)d_in[0];
  const int* tags = (const int*)d_in[1];
  const float* emb_w = (const float*)d_in[2];
  const float* W_ih = (const float*)d_in[3];
  const float* W_hh = (const float*)d_in[4];
  const float* b_ih = (const float*)d_in[5];
  const float* b_hh = (const float*)d_in[6];
  const float* W1 = (const float*)d_in[7];
  const float* b1 = (const float*)d_in[8];
  const float* W2 = (const float*)d_in[9];
  const float* b2 = (const float*)d_in[10];
  float* out = (float*)d_out;

  char* ws = (char*)d_ws;
  short* wih_pk = (short*)(ws + OFF_WIH);
  short* whh_pk = (short*)(ws + OFF_WHH);
  short* x_bf = (short*)(ws + OFF_X);
  float* bias_pk = (float*)(ws + OFF_BIAS);
  short* h_bf = (short*)(ws + OFF_H);
  unsigned* flags = (unsigned*)(ws + OFF_FLAGS);

  void* args[] = {&tokens, &tags, &emb_w, &W_ih, &W_hh, &b_ih, &b_hh,
                  &W1, &b1, &W2, &b2, &out,
                  &wih_pk, &whh_pk, &x_bf, &bias_pk, &h_bf, &flags};
  dim3 grid(256), block(256);
  hipLaunchCooperativeKernel(reinterpret_cast<void*>(&lstm_tag_kernel), grid,
                             block, args, 0, stream);
}